// Round 1
// baseline (432.452 us; speedup 1.0000x reference)
//
#include <hip/hip_runtime.h>
#include <cstdint>

#define V_TH 1.0f
#define RHO 0.9f
#define ADAPT 0.1f

static constexpr int B = 64, T = 8, C = 2, H = 128, W = 128;
static constexpr int H1 = 64, W1 = 64, C1 = 16;
static constexpr int H2 = 32, W2 = 32, C2 = 32;
static constexpr int FLAT = C2 * H2 * W2;   // 32768
static constexpr int R = B * T;             // 512

// workspace layout (bytes)
static constexpr size_t OFF_S1   = 0;                         // uint8 [R*64*64*16] = 33554432
static constexpr size_t OFF_BITS = 33554432;                  // uint32 [R*1024]   = 2097152 B
static constexpr size_t OFF_PWT  = OFF_BITS + 2097152;        // float [32768*64]  = 8388608 B
static constexpr size_t OFF_PROJ = OFF_PWT + 8388608;         // float [R*64]      = 131072 B
static constexpr size_t OFF_CNT  = OFF_PROJ + (size_t)R * 64 * 4; // uint [1]

// ---------------- init: proj <- bias, counter <- 0 ----------------
__global__ void k_init(float* __restrict__ proj, const float* __restrict__ pb,
                       unsigned int* __restrict__ cnt) {
  int tid = blockIdx.x * 256 + threadIdx.x;
  if (tid < R * 64) proj[tid] = pb[tid & 63];
  if (tid == 0) *cnt = 0u;
}

// ---------------- proj_w transpose+permute: pwt[(p*32+c)*64+d] = pw[d*32768 + c*1024 + p]
__global__ void k_transpose(const float* __restrict__ pw, float* __restrict__ pwt) {
  int tid = blockIdx.x * 256 + threadIdx.x;   // 0 .. 2M-1
  int d = tid & 63, j = tid >> 6;
  int c = j & 31, p = j >> 5;
  pwt[tid] = pw[(size_t)d * FLAT + c * 1024 + p];
}

// ---------------- stage 1: conv(2->16, s2, p1) fused with LIF scan over T ----
__global__ __launch_bounds__(256) void k_conv1_lif1(
    const float* __restrict__ x, const float* __restrict__ w,
    const float* __restrict__ bias, const float* __restrict__ beta,
    uint8_t* __restrict__ s1) {
  __shared__ float sw[288];
  __shared__ float sb[16];
  __shared__ float sbeta[16];
  int tid = threadIdx.x;
  if (tid < 288) sw[tid] = w[tid];
  if (tid < 16) { sb[tid] = bias[tid]; sbeta[tid] = beta[tid]; }
  __syncthreads();
  int gid = blockIdx.x * 256 + tid;           // (b, h1, w1)
  int w1 = gid & 63, h1 = (gid >> 6) & 63, b = gid >> 12;
  float mem[16], bth[16];
#pragma unroll
  for (int c = 0; c < 16; ++c) { mem[c] = 0.f; bth[c] = 0.f; }
  for (int t = 0; t < T; ++t) {
    float acc[16];
#pragma unroll
    for (int c = 0; c < 16; ++c) acc[c] = sb[c];
    const float* xb = x + (size_t)(b * T + t) * C * H * W;
#pragma unroll
    for (int kh = 0; kh < 3; ++kh) {
      int y = h1 * 2 - 1 + kh;
      if (y < 0 || y >= H) continue;
#pragma unroll
      for (int kw = 0; kw < 3; ++kw) {
        int xx = w1 * 2 - 1 + kw;
        if (xx < 0 || xx >= W) continue;
#pragma unroll
        for (int ci = 0; ci < 2; ++ci) {
          float v = xb[ci * (H * W) + y * W + xx];
          if (v != 0.f) {
#pragma unroll
            for (int c = 0; c < 16; ++c)
              acc[c] += v * sw[((c * 2 + ci) * 3 + kh) * 3 + kw];
          }
        }
      }
    }
    // adaptive LIF, soft reset
    uint32_t by[4] = {0u, 0u, 0u, 0u};
#pragma unroll
    for (int c = 0; c < 16; ++c) {
      mem[c] = sbeta[c] * mem[c] + acc[c];
      float th = V_TH + bth[c];
      bool s = (mem[c] >= th);
      if (s) { mem[c] -= th; by[c >> 2] |= (1u << ((c & 3) * 8)); }
      bth[c] = RHO * bth[c] + (s ? ADAPT : 0.f);
    }
    uint4 pk; pk.x = by[0]; pk.y = by[1]; pk.z = by[2]; pk.w = by[3];
    *(uint4*)(s1 + ((size_t)((b * T + t) * H1 + h1) * W1 + w1) * 16) = pk;
  }
}

// ---------------- stage 2: conv(16->32, s2, p1) on binary s1, fused LIF -----
__global__ __launch_bounds__(256) void k_conv2_lif2(
    const uint8_t* __restrict__ s1, const float* __restrict__ w,
    const float* __restrict__ bias, const float* __restrict__ beta,
    uint32_t* __restrict__ bits, unsigned int* __restrict__ cnt) {
  __shared__ float sw[4608];  // [(ci*3+kh)*3+kw][co]
  __shared__ float sb[32];
  __shared__ float sbeta[32];
  __shared__ unsigned int sc;
  int tid = threadIdx.x;
  for (int i = tid; i < 4608; i += 256) {
    int co = i & 31;
    int rest = i >> 5;                        // (ci*3+kh)*3+kw
    int kw = rest % 3, kh = (rest / 3) % 3, ci = rest / 9;
    sw[i] = w[((co * 16 + ci) * 3 + kh) * 3 + kw];
  }
  if (tid < 32) { sb[tid] = bias[tid]; sbeta[tid] = beta[tid]; }
  if (tid == 0) sc = 0u;
  __syncthreads();
  int gid = blockIdx.x * 256 + tid;           // (b, h2, w2)
  int w2 = gid & 31, h2 = (gid >> 5) & 31, b = gid >> 10;
  float mem[32], bth[32];
#pragma unroll
  for (int c = 0; c < 32; ++c) { mem[c] = 0.f; bth[c] = 0.f; }
  unsigned int lc = 0;
  for (int t = 0; t < T; ++t) {
    int r = b * T + t;
    float acc[32];
#pragma unroll
    for (int c = 0; c < 32; ++c) acc[c] = sb[c];
    for (int kh = 0; kh < 3; ++kh) {
      int y = h2 * 2 - 1 + kh;
      if (y < 0 || y >= H1) continue;
      for (int kw = 0; kw < 3; ++kw) {
        int xx = w2 * 2 - 1 + kw;
        if (xx < 0 || xx >= W1) continue;
        uint4 m = *(const uint4*)(s1 + ((size_t)(r * H1 + y) * W1 + xx) * 16);
        uint32_t mw[4] = {m.x, m.y, m.z, m.w};
#pragma unroll
        for (int ci = 0; ci < 16; ++ci) {
          uint32_t byv = (mw[ci >> 2] >> ((ci & 3) * 8)) & 0xFFu;
          if (byv) {                          // spike is exactly 1
            const float* wp = &sw[((ci * 3 + kh) * 3 + kw) * 32];
#pragma unroll
            for (int co = 0; co < 32; ++co) acc[co] += wp[co];
          }
        }
      }
    }
    uint32_t mask = 0;
#pragma unroll
    for (int c = 0; c < 32; ++c) {
      mem[c] = sbeta[c] * mem[c] + acc[c];
      float th = V_TH + bth[c];
      bool s = (mem[c] >= th);
      if (s) { mem[c] -= th; mask |= (1u << c); }
      bth[c] = RHO * bth[c] + (s ? ADAPT : 0.f);
    }
    bits[(size_t)r * 1024 + h2 * 32 + w2] = mask;
    lc += __popc(mask);
  }
  atomicAdd(&sc, lc);
  __syncthreads();
  if (tid == 0) atomicAdd(cnt, sc);
}

// ---------------- sparse proj GEMM: proj[r,d] += sum over set bits of pwt col
__global__ __launch_bounds__(64) void k_proj_gemm(
    const uint32_t* __restrict__ bits, const float* __restrict__ pwt,
    float* __restrict__ proj) {
  int rt = blockIdx.x >> 3, ks = blockIdx.x & 7;  // 64 row-tiles x 8 K-splits
  int d = threadIdx.x;
  float acc[8] = {0, 0, 0, 0, 0, 0, 0, 0};
  int w0 = ks * 128;
  for (int wi = 0; wi < 128; ++wi) {
    int word = w0 + wi;
#pragma unroll
    for (int ri = 0; ri < 8; ++ri) {
      uint32_t m = bits[(size_t)(rt * 8 + ri) * 1024 + word];
      while (m) {
        int c = __ffs(m) - 1;
        m &= m - 1;
        acc[ri] += pwt[((size_t)word * 32 + c) * 64 + d];
      }
    }
  }
#pragma unroll
  for (int ri = 0; ri < 8; ++ri)
    atomicAdd(&proj[(size_t)(rt * 8 + ri) * 64 + d], acc[ri]);
}

// ---------------- MHA + mean + output LIF + classifier + sparsity ----------
__global__ __launch_bounds__(64) void k_attn_final(
    const float* __restrict__ proj, const float* __restrict__ wq,
    const float* __restrict__ wk, const float* __restrict__ wv,
    const float* __restrict__ wo, const float* __restrict__ clsw,
    const float* __restrict__ clsb, const unsigned int* __restrict__ cnt,
    float* __restrict__ out) {
  __shared__ float sp[8 * 65], sq[8 * 65], sk[8 * 65], sv[8 * 65];
  __shared__ float satt[4][8][8];
  __shared__ float sob[64];
  int b = blockIdx.x, tid = threadIdx.x;
  for (int t = 0; t < 8; ++t)
    sp[t * 65 + tid] = proj[((size_t)b * 8 + t) * 64 + tid];
  __syncthreads();
  for (int t = 0; t < 8; ++t) {
    float qa = 0.f, ka = 0.f, va = 0.f;
    for (int e = 0; e < 64; ++e) {
      float pe = sp[t * 65 + e];
      qa += pe * wq[tid * 64 + e];
      ka += pe * wk[tid * 64 + e];
      va += pe * wv[tid * 64 + e];
    }
    sq[t * 65 + tid] = qa; sk[t * 65 + tid] = ka; sv[t * 65 + tid] = va;
  }
  __syncthreads();
  int qt = tid >> 3, kt = tid & 7;
  for (int h = 0; h < 4; ++h) {
    float s = 0.f;
    for (int j = 0; j < 16; ++j)
      s += sq[qt * 65 + h * 16 + j] * sk[kt * 65 + h * 16 + j];
    satt[h][qt][kt] = s * 0.25f;              // dh^-0.5 = 0.25
  }
  __syncthreads();
  if (tid < 32) {
    int h = tid >> 3, q2 = tid & 7;
    float m = -1e30f;
    for (int k2 = 0; k2 < 8; ++k2) m = fmaxf(m, satt[h][q2][k2]);
    float sum = 0.f;
    for (int k2 = 0; k2 < 8; ++k2) {
      float e = expf(satt[h][q2][k2] - m);
      satt[h][q2][k2] = e; sum += e;
    }
    float inv = 1.f / sum;
    for (int k2 = 0; k2 < 8; ++k2) satt[h][q2][k2] *= inv;
  }
  __syncthreads();
  int h = tid >> 4;
  float ob = 0.f;
  for (int q2 = 0; q2 < 8; ++q2) {
    float o = 0.f;
    for (int k2 = 0; k2 < 8; ++k2) o += satt[h][q2][k2] * sv[k2 * 65 + tid];
    ob += o;
  }
  ob *= 0.125f;                               // mean over T
  sob[tid] = ob;
  __syncthreads();
  float ctx = 0.f;                            // context = (mean_t o) @ wo.T
  for (int e = 0; e < 64; ++e) ctx += sob[e] * wo[tid * 64 + e];
  int spk = (ctx >= V_TH) ? 1 : 0;
  unsigned long long ball = __ballot(spk);
  if (tid < 2) {
    float lg = clsb[tid];
    for (int dd = 0; dd < 64; ++dd)
      if ((ball >> dd) & 1ull) lg += clsw[tid * 64 + dd];
    out[b * 2 + tid] = lg;
  }
  if (b == 0 && tid == 2)
    out[128] = 1.f - (float)(*cnt) / 16777216.f;
}

extern "C" void kernel_launch(void* const* d_in, const int* in_sizes, int n_in,
                              void* d_out, int out_size, void* d_ws, size_t ws_size,
                              hipStream_t stream) {
  const float* x    = (const float*)d_in[0];
  const float* c1w  = (const float*)d_in[1];
  const float* c1b  = (const float*)d_in[2];
  const float* c2w  = (const float*)d_in[3];
  const float* c2b  = (const float*)d_in[4];
  const float* bt1  = (const float*)d_in[5];
  const float* bt2  = (const float*)d_in[6];
  const float* pw   = (const float*)d_in[7];
  const float* pb   = (const float*)d_in[8];
  const float* wq   = (const float*)d_in[9];
  const float* wk   = (const float*)d_in[10];
  const float* wv   = (const float*)d_in[11];
  const float* wo   = (const float*)d_in[12];
  const float* clsw = (const float*)d_in[13];
  const float* clsb = (const float*)d_in[14];
  float* out = (float*)d_out;

  uint8_t* ws = (uint8_t*)d_ws;
  uint8_t*  s1   = ws + OFF_S1;
  uint32_t* bits = (uint32_t*)(ws + OFF_BITS);
  float*    pwt  = (float*)(ws + OFF_PWT);
  float*    proj = (float*)(ws + OFF_PROJ);
  unsigned int* cnt = (unsigned int*)(ws + OFF_CNT);

  k_init<<<128, 256, 0, stream>>>(proj, pb, cnt);
  k_transpose<<<8192, 256, 0, stream>>>(pw, pwt);
  k_conv1_lif1<<<1024, 256, 0, stream>>>(x, c1w, c1b, bt1, s1);
  k_conv2_lif2<<<256, 256, 0, stream>>>(s1, c2w, c2b, bt2, bits, cnt);
  k_proj_gemm<<<512, 64, 0, stream>>>(bits, pwt, proj);
  k_attn_final<<<64, 64, 0, stream>>>(proj, wq, wk, wv, wo, clsw, clsb, cnt, out);
}

// Round 3
// 379.013 us; speedup vs baseline: 1.1410x; 1.1410x over previous
//
#include <hip/hip_runtime.h>
#include <cstdint>

#define V_TH 1.0f
#define RHO 0.9f
#define ADAPT 0.1f

static constexpr int B = 64, T = 8, C = 2, H = 128, W = 128;
static constexpr int H1 = 64, W1 = 64;
static constexpr int H2 = 32, W2 = 32;
static constexpr int FLAT = 32 * H2 * W2;   // 32768
static constexpr int R = B * T;             // 512

// workspace layout (bytes)
static constexpr size_t OFF_XBITS = 0;                          // uint4 [131072]  = 2 MB
static constexpr size_t OFF_S1M   = 2097152;                    // u16 [512*64*64] = 4 MB
static constexpr size_t OFF_BITS  = OFF_S1M + 4194304;          // u32 [512*1024]  = 2 MB
static constexpr size_t OFF_PWT   = OFF_BITS + 2097152;         // f32 [32768*64]  = 8 MB
static constexpr size_t OFF_PROJ  = OFF_PWT + 8388608;          // f32 [512*64]
static constexpr size_t OFF_CNT   = OFF_PROJ + (size_t)R * 64 * 4;

// ---------------- init: proj <- bias, counter <- 0 ----------------
__global__ void k_init(float* __restrict__ proj, const float* __restrict__ pb,
                       unsigned int* __restrict__ cnt) {
  int tid = blockIdx.x * 256 + threadIdx.x;
  if (tid < R * 64) proj[tid] = pb[tid & 63];
  if (tid == 0) *cnt = 0u;
}

// ---------------- pack x (values in {0,1}) into bit rows: 128 bits per (b,t,ci,y)
__global__ __launch_bounds__(256) void k_pack(const float* __restrict__ x,
                                              uint4* __restrict__ xbits) {
  int wid = blockIdx.x * 4 + (threadIdx.x >> 6);   // row id, 0..131071
  int lane = threadIdx.x & 63;
  const float* xr = x + (size_t)wid * 128;
  float v0 = xr[lane];
  float v1 = xr[64 + lane];
  unsigned long long b0 = __ballot(v0 != 0.f);
  unsigned long long b1 = __ballot(v1 != 0.f);
  if (lane == 0) {
    uint4 pk;
    pk.x = (uint32_t)b0; pk.y = (uint32_t)(b0 >> 32);
    pk.z = (uint32_t)b1; pk.w = (uint32_t)(b1 >> 32);
    xbits[wid] = pk;
  }
}

// ---------------- tiled transpose: pwt[(p*32+c)*64+d] = pw[d*32768 + c*1024 + p]
__global__ __launch_bounds__(256) void k_transpose(const float* __restrict__ pw,
                                                   float* __restrict__ pwt) {
  __shared__ float tile[64 * 65];
  int c = blockIdx.x >> 4, pt = blockIdx.x & 15;
  int p0 = pt * 64;
  int lane = threadIdx.x & 63, quad = threadIdx.x >> 6;
#pragma unroll
  for (int it = 0; it < 16; ++it) {
    int d = it * 4 + quad;
    tile[d * 65 + lane] = pw[(size_t)d * FLAT + c * 1024 + p0 + lane];
  }
  __syncthreads();
#pragma unroll
  for (int it = 0; it < 16; ++it) {
    int pp = it * 4 + quad;
    pwt[((size_t)((p0 + pp) * 32 + c)) * 64 + lane] = tile[lane * 65 + pp];
  }
}

// extract 3 bits [2*w1-1, 2*w1+1] from a 128-bit row
__device__ __forceinline__ uint32_t win3(uint4 q, int w1) {
  int p = 2 * w1 - 1;
  int pp = p < 0 ? 0 : p;
  int wi = pp >> 5, off = pp & 31;
  uint32_t lo = (wi & 2) ? ((wi & 1) ? q.w : q.z) : ((wi & 1) ? q.y : q.x);
  uint32_t hi = (wi & 2) ? ((wi & 1) ? 0u : q.w) : ((wi & 1) ? q.z : q.y);
  uint32_t wn = (uint32_t)(((lo | ((uint64_t)hi << 32)) >> off) & 7u);
  if (p < 0) wn = (wn & 3u) << 1;
  return wn;
}

// ---------------- stage 1: conv(2->16,s2,p1) on bit rows, fused LIF ---------
__global__ __launch_bounds__(256) void k_conv1_lif1(
    const uint4* __restrict__ xbits, const float* __restrict__ w,
    const float* __restrict__ bias, const float* __restrict__ beta,
    uint16_t* __restrict__ s1m) {
  int gid = blockIdx.x * 256 + threadIdx.x;   // (b, h1, w1)
  int w1 = gid & 63, h1 = (gid >> 6) & 63, b = gid >> 12;
  float mem[16], bth[16];
#pragma unroll
  for (int c = 0; c < 16; ++c) { mem[c] = 0.f; bth[c] = 0.f; }
  for (int t = 0; t < T; ++t) {
    int r = b * T + t;
    uint32_t wn[6];
#pragma unroll
    for (int ci = 0; ci < 2; ++ci) {
#pragma unroll
      for (int kh = 0; kh < 3; ++kh) {
        int y = h1 * 2 - 1 + kh;
        uint4 q = {0u, 0u, 0u, 0u};
        if (y >= 0 && y < H) q = xbits[(size_t)(r * 2 + ci) * 128 + y];
        wn[ci * 3 + kh] = win3(q, w1);
      }
    }
    float acc[16];
#pragma unroll
    for (int c = 0; c < 16; ++c) acc[c] = bias[c];
#pragma unroll
    for (int ci = 0; ci < 2; ++ci)
#pragma unroll
      for (int kh = 0; kh < 3; ++kh)
#pragma unroll
        for (int kw = 0; kw < 3; ++kw) {
          float f = (float)((wn[ci * 3 + kh] >> kw) & 1u);
#pragma unroll
          for (int c = 0; c < 16; ++c)
            acc[c] += f * w[((c * 2 + ci) * 3 + kh) * 3 + kw];
        }
    uint32_t mask = 0;
#pragma unroll
    for (int c = 0; c < 16; ++c) {
      mem[c] = beta[c] * mem[c] + acc[c];
      float th = V_TH + bth[c];
      bool s = (mem[c] >= th);
      if (s) { mem[c] -= th; mask |= (1u << c); }
      bth[c] = RHO * bth[c] + (s ? ADAPT : 0.f);
    }
    s1m[(size_t)(r * H1 + h1) * W1 + w1] = (uint16_t)mask;
  }
}

// ---------------- stage 2: conv(16->32,s2,p1), lane = output channel --------
__global__ __launch_bounds__(256) void k_conv2_lif2(
    const uint16_t* __restrict__ s1m, const float* __restrict__ w,
    const float* __restrict__ bias, const float* __restrict__ beta,
    uint32_t* __restrict__ bits, unsigned int* __restrict__ cnt) {
  __shared__ float sw[144 * 32];     // [(ci*3+kh)*3+kw][co]
  __shared__ unsigned int sc;
  int tid = threadIdx.x;
  for (int i = tid; i < 144 * 32; i += 256) {
    int co = i & 31;
    int rest = i >> 5;               // ci*9 + kh*3 + kw
    int kw = rest % 3, kh = (rest / 3) % 3, ci = rest / 9;
    sw[i] = w[((co * 16 + ci) * 3 + kh) * 3 + kw];
  }
  if (tid == 0) sc = 0u;
  __syncthreads();
  int co = tid & 31;
  int px = (blockIdx.x * 256 + tid) >> 5;       // (b, h2, w2)
  int w2 = px & 31, h2 = (px >> 5) & 31, b = px >> 10;
  float bco = bias[co], betaco = beta[co];
  float mem = 0.f, bth = 0.f;
  unsigned int lc = 0;
  for (int t = 0; t < T; ++t) {
    int r = b * T + t;
    float acc = bco;
#pragma unroll
    for (int kh = 0; kh < 3; ++kh) {
      int y = h2 * 2 - 1 + kh;
#pragma unroll
      for (int kw = 0; kw < 3; ++kw) {
        int xx = w2 * 2 - 1 + kw;
        uint32_t m = 0;
        if (y >= 0 && xx >= 0)
          m = s1m[(size_t)(r * H1 + y) * W1 + xx];
        const float* wp = &sw[(kh * 3 + kw) * 32 + co];
        while (m) {
          int ci = __ffs(m) - 1;
          m &= m - 1;
          acc += wp[ci * 288];                  // (ci*9)*32 = ci*288
        }
      }
    }
    mem = betaco * mem + acc;
    float th = V_TH + bth;
    bool s = (mem >= th);
    if (s) mem -= th;
    bth = RHO * bth + (s ? ADAPT : 0.f);
    unsigned long long ball = __ballot(s);
    int lane = tid & 63;
    if (lane == 0) {
      bits[(size_t)r * 1024 + (px & 1023)] = (uint32_t)ball;
      lc += __popcll(ball);
    } else if (lane == 32) {
      // this lane's own px is already px0+1; write the high half to ITS pixel
      bits[(size_t)r * 1024 + (px & 1023)] = (uint32_t)(ball >> 32);
    }
  }
  if ((tid & 63) == 0) atomicAdd(&sc, lc);
  __syncthreads();
  if (tid == 0) atomicAdd(cnt, sc);
}

// ---------------- sparse proj GEMM ----------------
__global__ __launch_bounds__(64) void k_proj_gemm(
    const uint32_t* __restrict__ bits, const float* __restrict__ pwt,
    float* __restrict__ proj) {
  int rt = blockIdx.x >> 6, ks = blockIdx.x & 63;  // 64 row-tiles x 64 K-splits
  int d = threadIdx.x;
  float acc[8] = {0, 0, 0, 0, 0, 0, 0, 0};
  int w0 = ks * 16;
  for (int wi = 0; wi < 16; ++wi) {
    int word = w0 + wi;
#pragma unroll
    for (int ri = 0; ri < 8; ++ri) {
      uint32_t m = bits[(size_t)(rt * 8 + ri) * 1024 + word];
      while (m) {
        int c = __ffs(m) - 1;
        m &= m - 1;
        acc[ri] += pwt[((size_t)word * 32 + c) * 64 + d];
      }
    }
  }
#pragma unroll
  for (int ri = 0; ri < 8; ++ri)
    atomicAdd(&proj[(size_t)(rt * 8 + ri) * 64 + d], acc[ri]);
}

// ---------------- MHA + mean + output LIF + classifier + sparsity ----------
__global__ __launch_bounds__(64) void k_attn_final(
    const float* __restrict__ proj, const float* __restrict__ wq,
    const float* __restrict__ wk, const float* __restrict__ wv,
    const float* __restrict__ wo, const float* __restrict__ clsw,
    const float* __restrict__ clsb, const unsigned int* __restrict__ cnt,
    float* __restrict__ out) {
  __shared__ float sp[8 * 65], sq[8 * 65], sk[8 * 65], sv[8 * 65];
  __shared__ float satt[4][8][8];
  __shared__ float sob[64];
  int b = blockIdx.x, tid = threadIdx.x;
  for (int t = 0; t < 8; ++t)
    sp[t * 65 + tid] = proj[((size_t)b * 8 + t) * 64 + tid];
  __syncthreads();
  for (int t = 0; t < 8; ++t) {
    float qa = 0.f, ka = 0.f, va = 0.f;
    for (int e = 0; e < 64; ++e) {
      float pe = sp[t * 65 + e];
      qa += pe * wq[tid * 64 + e];
      ka += pe * wk[tid * 64 + e];
      va += pe * wv[tid * 64 + e];
    }
    sq[t * 65 + tid] = qa; sk[t * 65 + tid] = ka; sv[t * 65 + tid] = va;
  }
  __syncthreads();
  int qt = tid >> 3, kt = tid & 7;
  for (int h = 0; h < 4; ++h) {
    float s = 0.f;
    for (int j = 0; j < 16; ++j)
      s += sq[qt * 65 + h * 16 + j] * sk[kt * 65 + h * 16 + j];
    satt[h][qt][kt] = s * 0.25f;
  }
  __syncthreads();
  if (tid < 32) {
    int h = tid >> 3, q2 = tid & 7;
    float m = -1e30f;
    for (int k2 = 0; k2 < 8; ++k2) m = fmaxf(m, satt[h][q2][k2]);
    float sum = 0.f;
    for (int k2 = 0; k2 < 8; ++k2) {
      float e = expf(satt[h][q2][k2] - m);
      satt[h][q2][k2] = e; sum += e;
    }
    float inv = 1.f / sum;
    for (int k2 = 0; k2 < 8; ++k2) satt[h][q2][k2] *= inv;
  }
  __syncthreads();
  int h = tid >> 4;
  float ob = 0.f;
  for (int q2 = 0; q2 < 8; ++q2) {
    float o = 0.f;
    for (int k2 = 0; k2 < 8; ++k2) o += satt[h][q2][k2] * sv[k2 * 65 + tid];
    ob += o;
  }
  ob *= 0.125f;
  sob[tid] = ob;
  __syncthreads();
  float ctx = 0.f;
  for (int e = 0; e < 64; ++e) ctx += sob[e] * wo[tid * 64 + e];
  int spk = (ctx >= V_TH) ? 1 : 0;
  unsigned long long ball = __ballot(spk);
  if (tid < 2) {
    float lg = clsb[tid];
    for (int dd = 0; dd < 64; ++dd)
      if ((ball >> dd) & 1ull) lg += clsw[tid * 64 + dd];
    out[b * 2 + tid] = lg;
  }
  if (b == 0 && tid == 2)
    out[128] = 1.f - (float)(*cnt) / 16777216.f;
}

extern "C" void kernel_launch(void* const* d_in, const int* in_sizes, int n_in,
                              void* d_out, int out_size, void* d_ws, size_t ws_size,
                              hipStream_t stream) {
  const float* x    = (const float*)d_in[0];
  const float* c1w  = (const float*)d_in[1];
  const float* c1b  = (const float*)d_in[2];
  const float* c2w  = (const float*)d_in[3];
  const float* c2b  = (const float*)d_in[4];
  const float* bt1  = (const float*)d_in[5];
  const float* bt2  = (const float*)d_in[6];
  const float* pw   = (const float*)d_in[7];
  const float* pb   = (const float*)d_in[8];
  const float* wq   = (const float*)d_in[9];
  const float* wk   = (const float*)d_in[10];
  const float* wv   = (const float*)d_in[11];
  const float* wo   = (const float*)d_in[12];
  const float* clsw = (const float*)d_in[13];
  const float* clsb = (const float*)d_in[14];
  float* out = (float*)d_out;

  uint8_t* ws = (uint8_t*)d_ws;
  uint4*    xbits = (uint4*)(ws + OFF_XBITS);
  uint16_t* s1m   = (uint16_t*)(ws + OFF_S1M);
  uint32_t* bits  = (uint32_t*)(ws + OFF_BITS);
  float*    pwt   = (float*)(ws + OFF_PWT);
  float*    proj  = (float*)(ws + OFF_PROJ);
  unsigned int* cnt = (unsigned int*)(ws + OFF_CNT);

  k_init<<<128, 256, 0, stream>>>(proj, pb, cnt);
  k_pack<<<32768, 256, 0, stream>>>(x, xbits);
  k_transpose<<<512, 256, 0, stream>>>(pw, pwt);
  k_conv1_lif1<<<1024, 256, 0, stream>>>(xbits, c1w, c1b, bt1, s1m);
  k_conv2_lif2<<<8192, 256, 0, stream>>>(s1m, c2w, c2b, bt2, bits, cnt);
  k_proj_gemm<<<4096, 64, 0, stream>>>(bits, pwt, proj);
  k_attn_final<<<64, 64, 0, stream>>>(proj, wq, wk, wv, wo, clsw, clsb, cnt, out);
}

// Round 5
// 275.622 us; speedup vs baseline: 1.5690x; 1.3751x over previous
//
#include <hip/hip_runtime.h>
#include <cstdint>

#define V_TH 1.0f
#define RHO 0.9f
#define ADAPT 0.1f

static constexpr int B = 64, T = 8, C = 2, H = 128, W = 128;
static constexpr int H1 = 64, W1 = 64;
static constexpr int H2 = 32, W2 = 32;
static constexpr int FLAT = 32 * H2 * W2;   // 32768
static constexpr int R = B * T;             // 512

// workspace layout (bytes)
static constexpr size_t OFF_XBITS = 0;                          // uint4 [131072]   = 2 MB
static constexpr size_t OFF_S1M   = 2097152;                    // u16 [512*64*64]  = 4 MB
static constexpr size_t OFF_TRIP  = OFF_S1M + 4194304;          // u64 [512*64*32]  = 8 MB
static constexpr size_t OFF_BITS  = OFF_TRIP + 8388608;         // u32 [512*1024]   = 2 MB
static constexpr size_t OFF_PWT   = OFF_BITS + 2097152;         // f32 [32768*64]   = 8 MB
static constexpr size_t OFF_PROJ  = OFF_PWT + 8388608;          // f32 [512*64]
static constexpr size_t OFF_CNT   = OFF_PROJ + (size_t)R * 64 * 4;

__device__ __forceinline__ int ffs64(uint64_t m) {
  return __ffsll((unsigned long long)m);
}

// ---------------- init: proj <- bias, counter <- 0 ----------------
__global__ void k_init(float* __restrict__ proj, const float* __restrict__ pb,
                       unsigned int* __restrict__ cnt) {
  int tid = blockIdx.x * 256 + threadIdx.x;
  if (tid < R * 64) proj[tid] = pb[tid & 63];
  if (tid == 0) *cnt = 0u;
}

// ---------------- pack x (values in {0,1}) into bit rows: 128 bits per (b,t,ci,y)
__global__ __launch_bounds__(256) void k_pack(const float* __restrict__ x,
                                              uint4* __restrict__ xbits) {
  int wid = blockIdx.x * 4 + (threadIdx.x >> 6);   // row id, 0..131071
  int lane = threadIdx.x & 63;
  const float* xr = x + (size_t)wid * 128;
  float v0 = xr[lane];
  float v1 = xr[64 + lane];
  unsigned long long b0 = __ballot(v0 != 0.f);
  unsigned long long b1 = __ballot(v1 != 0.f);
  if (lane == 0) {
    uint4 pk;
    pk.x = (uint32_t)b0; pk.y = (uint32_t)(b0 >> 32);
    pk.z = (uint32_t)b1; pk.w = (uint32_t)(b1 >> 32);
    xbits[wid] = pk;
  }
}

// ---------------- tiled transpose: pwt[(p*32+c)*64+d] = pw[d*32768 + c*1024 + p]
__global__ __launch_bounds__(256) void k_transpose(const float* __restrict__ pw,
                                                   float* __restrict__ pwt) {
  __shared__ float tile[64 * 65];
  int c = blockIdx.x >> 4, pt = blockIdx.x & 15;
  int p0 = pt * 64;
  int lane = threadIdx.x & 63, quad = threadIdx.x >> 6;
#pragma unroll
  for (int it = 0; it < 16; ++it) {
    int d = it * 4 + quad;
    tile[d * 65 + lane] = pw[(size_t)d * FLAT + c * 1024 + p0 + lane];
  }
  __syncthreads();
#pragma unroll
  for (int it = 0; it < 16; ++it) {
    int pp = it * 4 + quad;
    pwt[((size_t)((p0 + pp) * 32 + c)) * 64 + lane] = tile[lane * 65 + pp];
  }
}

// extract 3 bits [2*w1-1, 2*w1+1] from a 128-bit row
__device__ __forceinline__ uint32_t win3(uint4 q, int w1) {
  int p = 2 * w1 - 1;
  int pp = p < 0 ? 0 : p;
  int wi = pp >> 5, off = pp & 31;
  uint32_t lo = (wi & 2) ? ((wi & 1) ? q.w : q.z) : ((wi & 1) ? q.y : q.x);
  uint32_t hi = (wi & 2) ? ((wi & 1) ? 0u : q.w) : ((wi & 1) ? q.z : q.y);
  uint32_t wn = (uint32_t)(((lo | ((uint64_t)hi << 32)) >> off) & 7u);
  if (p < 0) wn = (wn & 3u) << 1;
  return wn;
}

// ---------------- stage 1: sparse-scan conv(2->16,s2,p1), fused LIF ---------
// weights in LDS as [j][c], j = ci*9+kh*3+kw (18 rows), row stride 68 dwords
__global__ __launch_bounds__(256) void k_conv1_lif1(
    const uint4* __restrict__ xbits, const float* __restrict__ w,
    const float* __restrict__ bias, const float* __restrict__ beta,
    uint16_t* __restrict__ s1m) {
  __shared__ float sw1[18 * 68];
  for (int i = threadIdx.x; i < 288; i += 256) {
    int c = i / 18, j = i % 18;         // source linear i = c*18 + j
    sw1[j * 68 + c] = w[i];
  }
  __syncthreads();
  int gid = blockIdx.x * 256 + threadIdx.x;   // (b, h1, w1)
  int w1 = gid & 63, h1 = (gid >> 6) & 63, b = gid >> 12;
  float bias_r[16], beta_r[16];
#pragma unroll
  for (int c = 0; c < 16; ++c) { bias_r[c] = bias[c]; beta_r[c] = beta[c]; }
  float mem[16], bth[16];
#pragma unroll
  for (int c = 0; c < 16; ++c) { mem[c] = 0.f; bth[c] = 0.f; }
  for (int t = 0; t < T; ++t) {
    int r = b * T + t;
    uint32_t M = 0;
#pragma unroll
    for (int ci = 0; ci < 2; ++ci) {
#pragma unroll
      for (int kh = 0; kh < 3; ++kh) {
        int y = h1 * 2 - 1 + kh;
        uint4 q = {0u, 0u, 0u, 0u};
        if (y >= 0 && y < H) q = xbits[(size_t)(r * 2 + ci) * 128 + y];
        M |= win3(q, w1) << ((ci * 3 + kh) * 3);
      }
    }
    float acc[16];
#pragma unroll
    for (int c = 0; c < 16; ++c) acc[c] = bias_r[c];
    while (M) {                          // ascending j == (ci,kh,kw) lex order
      int j = __ffs(M) - 1; M &= M - 1;
      const float4* wr = (const float4*)&sw1[j * 68];
      float4 a0 = wr[0], a1 = wr[1], a2 = wr[2], a3 = wr[3];
      acc[0] += a0.x; acc[1] += a0.y; acc[2] += a0.z; acc[3] += a0.w;
      acc[4] += a1.x; acc[5] += a1.y; acc[6] += a1.z; acc[7] += a1.w;
      acc[8] += a2.x; acc[9] += a2.y; acc[10] += a2.z; acc[11] += a2.w;
      acc[12] += a3.x; acc[13] += a3.y; acc[14] += a3.z; acc[15] += a3.w;
    }
    uint32_t mask = 0;
#pragma unroll
    for (int c = 0; c < 16; ++c) {
      mem[c] = beta_r[c] * mem[c] + acc[c];
      float th = V_TH + bth[c];
      bool s = (mem[c] >= th);
      if (s) { mem[c] -= th; mask |= (1u << c); }
      bth[c] = RHO * bth[c] + (s ? ADAPT : 0.f);
    }
    s1m[(size_t)(r * H1 + h1) * W1 + w1] = (uint16_t)mask;
  }
}

// ---------------- repack s1 masks into 48-bit column triples per (r,y,w2) ---
__global__ __launch_bounds__(256) void k_repack(const uint16_t* __restrict__ s1m,
                                                uint64_t* __restrict__ trip) {
  int idx = blockIdx.x * 256 + threadIdx.x;   // (r, y, w2): 512*64*32
  int w2 = idx & 31, y = (idx >> 5) & 63, r = idx >> 11;
  const uint16_t* row = s1m + (size_t)(r * 64 + y) * 64;
  uint64_t m0 = (w2 > 0) ? row[2 * w2 - 1] : 0u;
  uint64_t m1 = row[2 * w2];
  uint64_t m2 = row[2 * w2 + 1];
  trip[idx] = m0 | (m1 << 16) | (m2 << 32);   // bit = kw*16 + ci
}

// ---------------- stage 2: conv(16->32,s2,p1); 16 lanes/px, 2 co/lane -------
// sw2 layout: [kh][kw*16+ci][co] -> ds_read_b64 per spike covers both co
__global__ __launch_bounds__(256) void k_conv2_lif2(
    const uint64_t* __restrict__ trip, const float* __restrict__ w,
    const float* __restrict__ bias, const float* __restrict__ beta,
    uint32_t* __restrict__ bits, unsigned int* __restrict__ cnt) {
  __shared__ float sw2[3 * 48 * 32];   // 4608 floats = 18 KB
  __shared__ unsigned int sc;
  int tid = threadIdx.x;
  for (int i = tid; i < 4608; i += 256) {
    int co = i & 31;
    int ci = (i >> 5) & 15;
    int j3 = i >> 9;                   // kh*3 + kw
    int kw = j3 % 3, kh = j3 / 3;
    sw2[i] = w[((co * 16 + ci) * 3 + kh) * 3 + kw];
  }
  if (tid == 0) sc = 0u;
  __syncthreads();
  int li = tid & 15;                   // lane-in-quarter: co pair 2li, 2li+1
  int qw = (tid & 63) >> 4;            // quarter within wave
  int px = (blockIdx.x * 256 + tid) >> 4;       // (b, h2, w2)
  int w2 = px & 31, h2 = (px >> 5) & 31, b = px >> 10;
  float b0 = bias[2 * li], b1 = bias[2 * li + 1];
  float bt0 = beta[2 * li], bt1 = beta[2 * li + 1];
  float mem0 = 0.f, mem1 = 0.f, a0 = 0.f, a1 = 0.f;  // a* = adaptive thresholds
  unsigned int lc = 0;
  for (int t = 0; t < T; ++t) {
    int r = b * T + t;
    float acc0 = b0, acc1 = b1;
#pragma unroll
    for (int kh = 0; kh < 3; ++kh) {
      int y = 2 * h2 - 1 + kh;
      uint64_t M = 0;
      if (y >= 0 && y < 64) M = trip[(size_t)(r * 64 + y) * 32 + w2];
      const float* basep = &sw2[kh * 1536 + (li << 1)];
      while (M) {                      // ascending = (kw,ci) lex order
        int idx = ffs64(M) - 1; M &= M - 1;
        float2 wv = *(const float2*)&basep[idx << 5];
        acc0 += wv.x; acc1 += wv.y;
      }
    }
    mem0 = bt0 * mem0 + acc0;
    mem1 = bt1 * mem1 + acc1;
    float th0 = V_TH + a0, th1 = V_TH + a1;
    bool s0 = (mem0 >= th0), s1 = (mem1 >= th1);
    if (s0) mem0 -= th0;
    if (s1) mem1 -= th1;
    a0 = RHO * a0 + (s0 ? ADAPT : 0.f);
    a1 = RHO * a1 + (s1 ? ADAPT : 0.f);
    unsigned long long ball0 = __ballot(s0);
    unsigned long long ball1 = __ballot(s1);
    uint32_t lo = (uint32_t)(ball0 >> (qw * 16)) & 0xFFFFu;
    uint32_t hi = (uint32_t)(ball1 >> (qw * 16)) & 0xFFFFu;
    // spread each 16-bit mask to every-2nd bit and interleave (co=2i from lo)
    uint32_t ax = lo;
    ax = (ax | (ax << 8)) & 0x00FF00FFu;
    ax = (ax | (ax << 4)) & 0x0F0F0F0Fu;
    ax = (ax | (ax << 2)) & 0x33333333u;
    ax = (ax | (ax << 1)) & 0x55555555u;
    uint32_t bx = hi;
    bx = (bx | (bx << 8)) & 0x00FF00FFu;
    bx = (bx | (bx << 4)) & 0x0F0F0F0Fu;
    bx = (bx | (bx << 2)) & 0x33333333u;
    bx = (bx | (bx << 1)) & 0x55555555u;
    uint32_t mask32 = ax | (bx << 1);
    if (li == 0) {
      bits[(size_t)r * 1024 + (px & 1023)] = mask32;
      lc += __popc(mask32);
    }
  }
  if (li == 0) atomicAdd(&sc, lc);
  __syncthreads();
  if (tid == 0) atomicAdd(cnt, sc);
}

// ---------------- sparse proj GEMM ----------------
__global__ __launch_bounds__(64) void k_proj_gemm(
    const uint32_t* __restrict__ bits, const float* __restrict__ pwt,
    float* __restrict__ proj) {
  int rt = blockIdx.x >> 6, ks = blockIdx.x & 63;  // 64 row-tiles x 64 K-splits
  int d = threadIdx.x;
  float acc[8] = {0, 0, 0, 0, 0, 0, 0, 0};
  int w0 = ks * 16;
  for (int wi = 0; wi < 16; ++wi) {
    int word = w0 + wi;
#pragma unroll
    for (int ri = 0; ri < 8; ++ri) {
      uint32_t m = bits[(size_t)(rt * 8 + ri) * 1024 + word];
      while (m) {
        int c = __ffs(m) - 1;
        m &= m - 1;
        acc[ri] += pwt[((size_t)word * 32 + c) * 64 + d];
      }
    }
  }
#pragma unroll
  for (int ri = 0; ri < 8; ++ri)
    atomicAdd(&proj[(size_t)(rt * 8 + ri) * 64 + d], acc[ri]);
}

// ---------------- MHA + mean + output LIF + classifier + sparsity ----------
__global__ __launch_bounds__(64) void k_attn_final(
    const float* __restrict__ proj, const float* __restrict__ wq,
    const float* __restrict__ wk, const float* __restrict__ wv,
    const float* __restrict__ wo, const float* __restrict__ clsw,
    const float* __restrict__ clsb, const unsigned int* __restrict__ cnt,
    float* __restrict__ out) {
  __shared__ float sp[8 * 65], sq[8 * 65], sk[8 * 65], sv[8 * 65];
  __shared__ float satt[4][8][8];
  __shared__ float sob[64];
  int b = blockIdx.x, tid = threadIdx.x;
  for (int t = 0; t < 8; ++t)
    sp[t * 65 + tid] = proj[((size_t)b * 8 + t) * 64 + tid];
  __syncthreads();
  for (int t = 0; t < 8; ++t) {
    float qa = 0.f, ka = 0.f, va = 0.f;
    for (int e = 0; e < 64; ++e) {
      float pe = sp[t * 65 + e];
      qa += pe * wq[tid * 64 + e];
      ka += pe * wk[tid * 64 + e];
      va += pe * wv[tid * 64 + e];
    }
    sq[t * 65 + tid] = qa; sk[t * 65 + tid] = ka; sv[t * 65 + tid] = va;
  }
  __syncthreads();
  int qt = tid >> 3, kt = tid & 7;
  for (int h = 0; h < 4; ++h) {
    float s = 0.f;
    for (int j = 0; j < 16; ++j)
      s += sq[qt * 65 + h * 16 + j] * sk[kt * 65 + h * 16 + j];
    satt[h][qt][kt] = s * 0.25f;
  }
  __syncthreads();
  if (tid < 32) {
    int h = tid >> 3, q2 = tid & 7;
    float m = -1e30f;
    for (int k2 = 0; k2 < 8; ++k2) m = fmaxf(m, satt[h][q2][k2]);
    float sum = 0.f;
    for (int k2 = 0; k2 < 8; ++k2) {
      float e = expf(satt[h][q2][k2] - m);
      satt[h][q2][k2] = e; sum += e;
    }
    float inv = 1.f / sum;
    for (int k2 = 0; k2 < 8; ++k2) satt[h][q2][k2] *= inv;
  }
  __syncthreads();
  int h = tid >> 4;
  float ob = 0.f;
  for (int q2 = 0; q2 < 8; ++q2) {
    float o = 0.f;
    for (int k2 = 0; k2 < 8; ++k2) o += satt[h][q2][k2] * sv[k2 * 65 + tid];
    ob += o;
  }
  ob *= 0.125f;
  sob[tid] = ob;
  __syncthreads();
  float ctx = 0.f;
  for (int e = 0; e < 64; ++e) ctx += sob[e] * wo[tid * 64 + e];
  int spk = (ctx >= V_TH) ? 1 : 0;
  unsigned long long ball = __ballot(spk);
  if (tid < 2) {
    float lg = clsb[tid];
    for (int dd = 0; dd < 64; ++dd)
      if ((ball >> dd) & 1ull) lg += clsw[tid * 64 + dd];
    out[b * 2 + tid] = lg;
  }
  if (b == 0 && tid == 2)
    out[128] = 1.f - (float)(*cnt) / 16777216.f;
}

extern "C" void kernel_launch(void* const* d_in, const int* in_sizes, int n_in,
                              void* d_out, int out_size, void* d_ws, size_t ws_size,
                              hipStream_t stream) {
  const float* x    = (const float*)d_in[0];
  const float* c1w  = (const float*)d_in[1];
  const float* c1b  = (const float*)d_in[2];
  const float* c2w  = (const float*)d_in[3];
  const float* c2b  = (const float*)d_in[4];
  const float* bt1  = (const float*)d_in[5];
  const float* bt2  = (const float*)d_in[6];
  const float* pw   = (const float*)d_in[7];
  const float* pb   = (const float*)d_in[8];
  const float* wq   = (const float*)d_in[9];
  const float* wk   = (const float*)d_in[10];
  const float* wv   = (const float*)d_in[11];
  const float* wo   = (const float*)d_in[12];
  const float* clsw = (const float*)d_in[13];
  const float* clsb = (const float*)d_in[14];
  float* out = (float*)d_out;

  uint8_t* ws = (uint8_t*)d_ws;
  uint4*    xbits = (uint4*)(ws + OFF_XBITS);
  uint16_t* s1m   = (uint16_t*)(ws + OFF_S1M);
  uint64_t* trip  = (uint64_t*)(ws + OFF_TRIP);
  uint32_t* bits  = (uint32_t*)(ws + OFF_BITS);
  float*    pwt   = (float*)(ws + OFF_PWT);
  float*    proj  = (float*)(ws + OFF_PROJ);
  unsigned int* cnt = (unsigned int*)(ws + OFF_CNT);

  k_init<<<128, 256, 0, stream>>>(proj, pb, cnt);
  k_pack<<<32768, 256, 0, stream>>>(x, xbits);
  k_transpose<<<512, 256, 0, stream>>>(pw, pwt);
  k_conv1_lif1<<<1024, 256, 0, stream>>>(xbits, c1w, c1b, bt1, s1m);
  k_repack<<<4096, 256, 0, stream>>>(s1m, trip);
  k_conv2_lif2<<<4096, 256, 0, stream>>>(trip, c2w, c2b, bt2, bits, cnt);
  k_proj_gemm<<<4096, 64, 0, stream>>>(bits, pwt, proj);
  k_attn_final<<<64, 64, 0, stream>>>(proj, wq, wk, wv, wo, clsw, clsb, cnt, out);
}